// Round 12
// baseline (373.509 us; speedup 1.0000x reference)
//
#include <hip/hip_runtime.h>
#include <hip/hip_bf16.h>

typedef __attribute__((ext_vector_type(8))) short bf16x8;
typedef __attribute__((ext_vector_type(4))) float f32x4;

__device__ inline unsigned short f2bf(float x) {
  unsigned int u = __float_as_uint(x);
  unsigned int r = (u + 0x7fffu + ((u >> 16) & 1u)) >> 16;
  return (unsigned short)r;
}
__device__ inline float bf2f(unsigned short u) {
  return __uint_as_float(((unsigned int)u) << 16);
}

// ---- prep: weights (b<128) | zero cnt (128<=b<128+zB) | nodes->bf16 (rest) ----
__global__ __launch_bounds__(256) void prep_zero(
    const float* __restrict__ Wm, const float* __restrict__ w0,
    const float* __restrict__ w1, const float* __restrict__ w2,
    const float* __restrict__ Wn, const float* __restrict__ nodesF,
    unsigned short* __restrict__ CmbT, unsigned short* __restrict__ W0T,
    unsigned short* __restrict__ W1T, unsigned short* __restrict__ W2nT,
    unsigned short* __restrict__ nodesBF,
    int* __restrict__ cnt, int N, int zB, long n8)
{
  int b = blockIdx.x;
  if (b < 128) {
    int n = b;
    int k = threadIdx.x;
    CmbT[n*256 + k] = f2bf(Wm[k*128 + n]);
    W0T [n*256 + k] = f2bf(w0[k*128 + n]);
    W2nT[n*256 + k] = f2bf((k < 128) ? w2[k*128 + n] : Wn[(k-128)*128 + n]);
    if (k < 128) W1T[n*128 + k] = f2bf(w1[k*128 + n]);
  } else if (b < 128 + zB) {
    int base = (b - 128) * 2048 + threadIdx.x;
    #pragma unroll
    for (int it = 0; it < 8; ++it) {
      int i = base + it * 256;
      if (i < N) cnt[i] = 0;
    }
  } else {
    long base = (long)(b - 128 - zB) * 2048 + threadIdx.x;
    #pragma unroll
    for (int it = 0; it < 8; ++it) {
      long i = base + it * 256;
      if (i < n8) {
        const f32x4* p = reinterpret_cast<const f32x4*>(nodesF + i * 8);
        f32x4 a = p[0], c = p[1];
        bf16x8 o;
        o[0]=(short)f2bf(a[0]); o[1]=(short)f2bf(a[1]); o[2]=(short)f2bf(a[2]); o[3]=(short)f2bf(a[3]);
        o[4]=(short)f2bf(c[0]); o[5]=(short)f2bf(c[1]); o[6]=(short)f2bf(c[2]); o[7]=(short)f2bf(c[3]);
        *reinterpret_cast<bf16x8*>(nodesBF + i * 8) = o;
      }
    }
  }
}

// ---------------- counting sort of edges by receiver ----------------
__global__ __launch_bounds__(256) void hist_recv(
    const int* __restrict__ recv, int* __restrict__ cnt, int E)
{
  int e = blockIdx.x * 256 + threadIdx.x;
  if (e < E) atomicAdd(&cnt[recv[e]], 1);
}

// --- multi-block scan: A) chunk sums, B) scan 256 partials, C) apply ---
__global__ __launch_bounds__(256) void scanA(
    const int* __restrict__ cnt, int* __restrict__ partial, int N, int CH)
{
  __shared__ int sm[256];
  int b = blockIdx.x, t = threadIdx.x;
  int i = b * CH + t;
  int c = (t < CH && i < N) ? cnt[i] : 0;
  sm[t] = c; __syncthreads();
  for (int off = 128; off > 0; off >>= 1) {
    if (t < off) sm[t] += sm[t + off];
    __syncthreads();
  }
  if (t == 0) partial[b] = sm[0];
}

__global__ __launch_bounds__(256) void scanB(
    int* __restrict__ partial, int* __restrict__ offs, int N)
{
  __shared__ int sm[256];
  int t = threadIdx.x;
  int v = partial[t];
  sm[t] = v; __syncthreads();
  for (int off = 1; off < 256; off <<= 1) {
    int x = (t >= off) ? sm[t - off] : 0; __syncthreads();
    sm[t] += x; __syncthreads();
  }
  partial[t] = sm[t] - v;            // exclusive prefix
  if (t == 255) offs[N] = sm[255];   // total = E
}

__global__ __launch_bounds__(256) void scanC(
    const int* __restrict__ cnt, const int* __restrict__ partial,
    int* __restrict__ offs, int* __restrict__ cursor, int N, int CH)
{
  __shared__ int sm[256];
  int b = blockIdx.x, t = threadIdx.x;
  int i = b * CH + t;
  int c = (t < CH && i < N) ? cnt[i] : 0;
  sm[t] = c; __syncthreads();
  for (int off = 1; off < 256; off <<= 1) {
    int x = (t >= off) ? sm[t - off] : 0; __syncthreads();
    sm[t] += x; __syncthreads();
  }
  if (t < CH && i < N) {
    int excl = sm[t] - c + partial[b];
    offs[i] = excl;
    cursor[i] = excl;
  }
}

__global__ __launch_bounds__(256) void scatter_ids(
    const int* __restrict__ recv, const int* __restrict__ send,
    int* __restrict__ cursor, int2* __restrict__ pairs, int E)
{
  int e = blockIdx.x * 256 + threadIdx.x;
  if (e >= E) return;
  int pos = atomicAdd(&cursor[recv[e]], 1);
  pairs[pos] = make_int2(e, send[e]);
}

// ---------------- fused: gather-aggregate + 4 MFMA GEMMs + LayerNorm ---------
// 32-row tile, 4 waves; wave w: gathers 8 buckets, owns 32 GEMM cols.
__device__ inline bf16x8 ldsFragA(const unsigned short* tile, int rowBytes,
                                  int row, int kk, int lg) {
  int byteOff = row * rowBytes + ((((kk << 6) + (lg << 4))) ^ ((row & 7) << 4));
  return *reinterpret_cast<const bf16x8*>(
      reinterpret_cast<const char*>(tile) + byteOff);
}
__device__ inline bf16x8 glbFragB(const unsigned short* WT, int kElems,
                                  int n, int lr, int kk, int lg) {
  size_t el = (size_t)(n*16 + lr) * kElems + kk*32 + lg*8;
  return *reinterpret_cast<const bf16x8*>(WT + el);
}
__device__ inline bf16x8 fragA_nodesBF(const unsigned short* __restrict__ nodesBF,
                                       int grow, int kk, int lg) {
  return *reinterpret_cast<const bf16x8*>(nodesBF + (size_t)grow*128 + (kk << 5) + (lg << 3));
}

__global__ __launch_bounds__(256, 8) void fused_node(
    const unsigned short* __restrict__ nodesBF, const float* __restrict__ edgesF,
    const int* __restrict__ offs, const int2* __restrict__ pairs,
    const unsigned short* __restrict__ CmbT, const unsigned short* __restrict__ W0T,
    const unsigned short* __restrict__ W1T, const unsigned short* __restrict__ W2nT,
    const float* __restrict__ b0, const float* __restrict__ b1,
    const float* __restrict__ b2, const float* __restrict__ gam,
    const float* __restrict__ bet, float* __restrict__ out, int N)
{
  __shared__ unsigned short sS[32*256];   // 16KB gathered S tile; bufA/bufB alias
  __shared__ int sOffs[4][9];
  __shared__ float pS[4][32];
  __shared__ float pQ[4][32];

  unsigned short* bufA = sS;              // agg after G1; h1 after G3  [32][128]
  unsigned short* bufB = sS + 32*128;     // h0 after G2               [32][128]

  const int tid  = threadIdx.x;
  const int lane = tid & 63;
  const int w    = tid >> 6;           // wave 0..3
  const int lr = lane & 15;
  const int lg = lane >> 4;
  const int m0 = blockIdx.x * 32;

  // ---- gather: wave w aggregates nodes [m0+w*8, m0+w*8+8) ----
  {
    const int base = m0 + (w << 3);
    if (lane < 9) {
      int nidx = base + lane; if (nidx > N) nidx = N;
      sOffs[w][lane] = offs[nidx];
    }
    const int c4 = (lane & 31) * 4;
    const bool isNode = lane < 32;
    char* sSb = reinterpret_cast<char*>(sS);

    const int jstart = sOffs[w][0];
    const int jend   = sOffs[w][8];

    float4 acc = {0.f, 0.f, 0.f, 0.f};
    int nd = 0;
    int bound = sOffs[w][1];

    auto flush = [&]() {
      int row = (w << 3) + nd;
      ushort4 o;
      o.x = f2bf(acc.x); o.y = f2bf(acc.y); o.z = f2bf(acc.z); o.w = f2bf(acc.w);
      *reinterpret_cast<ushort4*>(sSb + row*512 + ((lane*8) ^ ((row & 7) << 4))) = o;
      acc.x = 0.f; acc.y = 0.f; acc.z = 0.f; acc.w = 0.f;
    };

    int j = jstart;
    if (j < jend) {
      const int jmax = jend - 1;
      int2 pb[8];
      #pragma unroll
      for (int k = 0; k < 8; ++k) pb[k] = pairs[min(j + k, jmax)];
      while (j < jend) {
        float4 v[8];
        if (isNode) {
          #pragma unroll
          for (int k = 0; k < 8; ++k) {
            ushort4 u = *reinterpret_cast<const ushort4*>(nodesBF + (size_t)pb[k].y*128 + c4);
            v[k].x = bf2f(u.x); v[k].y = bf2f(u.y); v[k].z = bf2f(u.z); v[k].w = bf2f(u.w);
          }
        } else {
          #pragma unroll
          for (int k = 0; k < 8; ++k)
            v[k] = *reinterpret_cast<const float4*>(edgesF + (size_t)pb[k].x*128 + c4);
        }
        int jn = j + 8;
        int2 pb2[8];
        if (jn < jend) {
          #pragma unroll
          for (int k = 0; k < 8; ++k) pb2[k] = pairs[min(jn + k, jmax)];
        }
        #pragma unroll
        for (int k = 0; k < 8; ++k) {
          int jj = j + k;
          if (jj < jend) {
            while (jj >= bound) {
              flush(); ++nd;
              bound = sOffs[w][nd + 1];
            }
            acc.x += v[k].x; acc.y += v[k].y; acc.z += v[k].z; acc.w += v[k].w;
          }
        }
        #pragma unroll
        for (int k = 0; k < 8; ++k) pb[k] = pb2[k];
        j = jn;
      }
    }
    while (nd < 8) { flush(); ++nd; }
  }

  f32x4 acc[2][2];   // [rowblock 0..2][coltile 0..2]; row=rb*16+lg*4+i, col=w*32+nn*16+lr
  bf16x8 b[2][4];
  int garow[2];
  #pragma unroll
  for (int rb = 0; rb < 2; ++rb) {
    int g = m0 + rb*16 + lr; if (g > N-1) g = N-1;
    garow[rb] = g;
  }

  // G1 first-half B loads (global) issue before the barrier
  #pragma unroll
  for (int nn = 0; nn < 2; ++nn)
    #pragma unroll
    for (int kk = 0; kk < 4; ++kk)
      b[nn][kk] = glbFragB(CmbT, 256, w*2 + nn, lr, kk, lg);

  __syncthreads();   // S1: sS(gathered) staged

  // ======== GEMM1: agg = S(32x256) @ Wm ========
  #pragma unroll
  for (int rb = 0; rb < 2; ++rb)
    #pragma unroll
    for (int nn = 0; nn < 2; ++nn) { acc[rb][nn][0]=0.f; acc[rb][nn][1]=0.f; acc[rb][nn][2]=0.f; acc[rb][nn][3]=0.f; }
  #pragma unroll
  for (int rb = 0; rb < 2; ++rb)
    #pragma unroll
    for (int kk = 0; kk < 4; ++kk) {
      bf16x8 a = ldsFragA(sS, 512, rb*16 + lr, kk, lg);
      #pragma unroll
      for (int nn = 0; nn < 2; ++nn)
        acc[rb][nn] = __builtin_amdgcn_mfma_f32_16x16x32_bf16(a, b[nn][kk], acc[rb][nn], 0, 0, 0);
    }
  #pragma unroll
  for (int nn = 0; nn < 2; ++nn)
    #pragma unroll
    for (int kk = 0; kk < 4; ++kk)
      b[nn][kk] = glbFragB(CmbT, 256, w*2 + nn, lr, kk + 4, lg);
  #pragma unroll
  for (int rb = 0; rb < 2; ++rb)
    #pragma unroll
    for (int kk = 0; kk < 4; ++kk) {
      bf16x8 a = ldsFragA(sS, 512, rb*16 + lr, kk + 4, lg);
      #pragma unroll
      for (int nn = 0; nn < 2; ++nn)
        acc[rb][nn] = __builtin_amdgcn_mfma_f32_16x16x32_bf16(a, b[nn][kk], acc[rb][nn], 0, 0, 0);
    }
  __syncthreads();   // S2: all sS reads done before bufA overwrite

  // epilogue G1 -> bufA (agg)
  #pragma unroll
  for (int rb = 0; rb < 2; ++rb)
    #pragma unroll
    for (int nn = 0; nn < 2; ++nn) {
      int col = w*32 + nn*16 + lr;
      #pragma unroll
      for (int i = 0; i < 4; ++i) {
        int r = rb*16 + lg*4 + i;
        *reinterpret_cast<unsigned short*>(
            reinterpret_cast<char*>(bufA) + r*256 + ((col << 1) ^ ((r & 7) << 4))) = f2bf(acc[rb][nn][i]);
      }
    }
  // G2 first-half B loads before the barrier
  #pragma unroll
  for (int nn = 0; nn < 2; ++nn)
    #pragma unroll
    for (int kk = 0; kk < 4; ++kk)
      b[nn][kk] = glbFragB(W0T, 256, w*2 + nn, lr, kk, lg);
  __syncthreads();   // S3: bufA(agg) ready

  // ======== GEMM2: h0 = relu([nodes, agg] @ w0 + b0) -> bufB ========
  #pragma unroll
  for (int rb = 0; rb < 2; ++rb)
    #pragma unroll
    for (int nn = 0; nn < 2; ++nn) { acc[rb][nn][0]=0.f; acc[rb][nn][1]=0.f; acc[rb][nn][2]=0.f; acc[rb][nn][3]=0.f; }
  #pragma unroll
  for (int rb = 0; rb < 2; ++rb)
    #pragma unroll
    for (int kk = 0; kk < 4; ++kk) {
      bf16x8 a = fragA_nodesBF(nodesBF, garow[rb], kk, lg);
      #pragma unroll
      for (int nn = 0; nn < 2; ++nn)
        acc[rb][nn] = __builtin_amdgcn_mfma_f32_16x16x32_bf16(a, b[nn][kk], acc[rb][nn], 0, 0, 0);
    }
  #pragma unroll
  for (int nn = 0; nn < 2; ++nn)
    #pragma unroll
    for (int kk = 0; kk < 4; ++kk)
      b[nn][kk] = glbFragB(W0T, 256, w*2 + nn, lr, kk + 4, lg);
  #pragma unroll
  for (int rb = 0; rb < 2; ++rb)
    #pragma unroll
    for (int kk = 0; kk < 4; ++kk) {
      bf16x8 a = ldsFragA(bufA, 256, rb*16 + lr, kk, lg);
      #pragma unroll
      for (int nn = 0; nn < 2; ++nn)
        acc[rb][nn] = __builtin_amdgcn_mfma_f32_16x16x32_bf16(a, b[nn][kk], acc[rb][nn], 0, 0, 0);
    }
  // epilogue G2 -> bufB (disjoint; no barrier)
  #pragma unroll
  for (int nn = 0; nn < 2; ++nn) {
    int col = w*32 + nn*16 + lr;
    float bb = b0[col];
    #pragma unroll
    for (int rb = 0; rb < 2; ++rb)
      #pragma unroll
      for (int i = 0; i < 4; ++i) {
        int r = rb*16 + lg*4 + i;
        float x = fmaxf(acc[rb][nn][i] + bb, 0.f);
        *reinterpret_cast<unsigned short*>(
            reinterpret_cast<char*>(bufB) + r*256 + ((col << 1) ^ ((r & 7) << 4))) = f2bf(x);
      }
  }
  // G3 B loads (K=128)
  #pragma unroll
  for (int nn = 0; nn < 2; ++nn)
    #pragma unroll
    for (int kk = 0; kk < 4; ++kk)
      b[nn][kk] = glbFragB(W1T, 128, w*2 + nn, lr, kk, lg);
  __syncthreads();   // S4: bufB(h0) ready; all bufA reads done

  // ======== GEMM3: h1 = relu(h0 @ w1 + b1) -> bufA ========
  #pragma unroll
  for (int rb = 0; rb < 2; ++rb)
    #pragma unroll
    for (int nn = 0; nn < 2; ++nn) { acc[rb][nn][0]=0.f; acc[rb][nn][1]=0.f; acc[rb][nn][2]=0.f; acc[rb][nn][3]=0.f; }
  #pragma unroll
  for (int rb = 0; rb < 2; ++rb)
    #pragma unroll
    for (int kk = 0; kk < 4; ++kk) {
      bf16x8 a = ldsFragA(bufB, 256, rb*16 + lr, kk, lg);
      #pragma unroll
      for (int nn = 0; nn < 2; ++nn)
        acc[rb][nn] = __builtin_amdgcn_mfma_f32_16x16x32_bf16(a, b[nn][kk], acc[rb][nn], 0, 0, 0);
    }
  // epilogue G3 -> bufA
  #pragma unroll
  for (int nn = 0; nn < 2; ++nn) {
    int col = w*32 + nn*16 + lr;
    float bb = b1[col];
    #pragma unroll
    for (int rb = 0; rb < 2; ++rb)
      #pragma unroll
      for (int i = 0; i < 4; ++i) {
        int r = rb*16 + lg*4 + i;
        float x = fmaxf(acc[rb][nn][i] + bb, 0.f);
        *reinterpret_cast<unsigned short*>(
            reinterpret_cast<char*>(bufA) + r*256 + ((col << 1) ^ ((r & 7) << 4))) = f2bf(x);
      }
  }
  // G4 first-half B loads
  #pragma unroll
  for (int nn = 0; nn < 2; ++nn)
    #pragma unroll
    for (int kk = 0; kk < 4; ++kk)
      b[nn][kk] = glbFragB(W2nT, 256, w*2 + nn, lr, kk, lg);
  __syncthreads();   // S5: bufA(h1) ready; all bufB reads done

  // ======== GEMM4: o = [h1, nodes] @ [w2; Wnode] + b2, LayerNorm ========
  #pragma unroll
  for (int rb = 0; rb < 2; ++rb)
    #pragma unroll
    for (int nn = 0; nn < 2; ++nn) { acc[rb][nn][0]=0.f; acc[rb][nn][1]=0.f; acc[rb][nn][2]=0.f; acc[rb][nn][3]=0.f; }
  #pragma unroll
  for (int rb = 0; rb < 2; ++rb)
    #pragma unroll
    for (int kk = 0; kk < 4; ++kk) {
      bf16x8 a = ldsFragA(bufA, 256, rb*16 + lr, kk, lg);
      #pragma unroll
      for (int nn = 0; nn < 2; ++nn)
        acc[rb][nn] = __builtin_amdgcn_mfma_f32_16x16x32_bf16(a, b[nn][kk], acc[rb][nn], 0, 0, 0);
    }
  #pragma unroll
  for (int nn = 0; nn < 2; ++nn)
    #pragma unroll
    for (int kk = 0; kk < 4; ++kk)
      b[nn][kk] = glbFragB(W2nT, 256, w*2 + nn, lr, kk + 4, lg);
  #pragma unroll
  for (int rb = 0; rb < 2; ++rb)
    #pragma unroll
    for (int kk = 0; kk < 4; ++kk) {
      bf16x8 a = fragA_nodesBF(nodesBF, garow[rb], kk, lg);
      #pragma unroll
      for (int nn = 0; nn < 2; ++nn)
        acc[rb][nn] = __builtin_amdgcn_mfma_f32_16x16x32_bf16(a, b[nn][kk], acc[rb][nn], 0, 0, 0);
    }
  // bias
  #pragma unroll
  for (int nn = 0; nn < 2; ++nn) {
    float bb = b2[w*32 + nn*16 + lr];
    #pragma unroll
    for (int rb = 0; rb < 2; ++rb)
      #pragma unroll
      for (int i = 0; i < 4; ++i) acc[rb][nn][i] += bb;
  }

  // ---- LayerNorm: cross-wave row reduction via LDS partials ----
  float rs[2][4], rq[2][4];
  #pragma unroll
  for (int rb = 0; rb < 2; ++rb)
    #pragma unroll
    for (int i = 0; i < 4; ++i) {
      float a0 = acc[rb][0][i], a1 = acc[rb][1][i];
      rs[rb][i] = a0 + a1;
      rq[rb][i] = a0*a0 + a1*a1;
    }
  #pragma unroll
  for (int msk = 1; msk < 16; msk <<= 1)
    #pragma unroll
    for (int rb = 0; rb < 2; ++rb)
      #pragma unroll
      for (int i = 0; i < 4; ++i) {
        rs[rb][i] += __shfl_xor(rs[rb][i], msk);
        rq[rb][i] += __shfl_xor(rq[rb][i], msk);
      }
  if (lr == 0) {
    #pragma unroll
    for (int rb = 0; rb < 2; ++rb)
      #pragma unroll
      for (int i = 0; i < 4; ++i) {
        int r = rb*16 + lg*4 + i;
        pS[w][r] = rs[rb][i];
        pQ[w][r] = rq[rb][i];
      }
  }
  __syncthreads();

  float gmul[2], gadd[2];
  #pragma unroll
  for (int nn = 0; nn < 2; ++nn) {
    int col = w*32 + nn*16 + lr;
    gmul[nn] = gam[col]; gadd[nn] = bet[col];
  }
  #pragma unroll
  for (int rb = 0; rb < 2; ++rb)
    #pragma unroll
    for (int i = 0; i < 4; ++i) {
      int r = rb*16 + lg*4 + i;
      float sum = pS[0][r] + pS[1][r] + pS[2][r] + pS[3][r];
      float sq  = pQ[0][r] + pQ[1][r] + pQ[2][r] + pQ[3][r];
      float mean = sum * (1.f/128.f);
      float var  = fmaxf(sq * (1.f/128.f) - mean*mean, 0.f);
      float rstd = rsqrtf(var + 1e-6f);
      int grow = m0 + r;
      if (grow < N) {
        #pragma unroll
        for (int nn = 0; nn < 2; ++nn) {
          int col = w*32 + nn*16 + lr;
          out[(size_t)grow*128 + col] = (acc[rb][nn][i] - mean) * rstd * gmul[nn] + gadd[nn];
        }
      }
    }
}

extern "C" void kernel_launch(void* const* d_in, const int* in_sizes, int n_in,
                              void* d_out, int out_size, void* d_ws, size_t ws_size,
                              hipStream_t stream) {
  const float* nodes     = (const float*)d_in[0];
  const float* edges     = (const float*)d_in[1];
  const int*   senders   = (const int*)d_in[2];
  const int*   receivers = (const int*)d_in[3];
  const float* Wm  = (const float*)d_in[4];
  const float* Wn  = (const float*)d_in[5];
  const float* w0  = (const float*)d_in[6];
  const float* b0  = (const float*)d_in[7];
  const float* w1  = (const float*)d_in[8];
  const float* b1  = (const float*)d_in[9];
  const float* w2  = (const float*)d_in[10];
  const float* b2  = (const float*)d_in[11];
  const float* gam = (const float*)d_in[12];
  const float* bet = (const float*)d_in[13];
  const int N = in_sizes[0] / 128;
  const int E = in_sizes[1] / 128;

  char* ws = (char*)d_ws;
  size_t off = 0;
  unsigned short* nodesBF = (unsigned short*)(ws + off); off += (size_t)N * 128 * 2;
  int2* pairs = (int2*)(ws + off);                       off += (size_t)E * 8;
  unsigned short* CmbT = (unsigned short*)(ws + off);    off += 128*256*2;
  unsigned short* W0T  = (unsigned short*)(ws + off);    off += 128*256*2;
  unsigned short* W1T  = (unsigned short*)(ws + off);    off += 128*128*2;
  unsigned short* W2nT = (unsigned short*)(ws + off);    off += 128*256*2;
  int* cnt     = (int*)(ws + off);                       off += (size_t)N * 4;
  int* offs    = (int*)(ws + off);                       off += (size_t)(N + 1) * 4;
  int* cursor  = (int*)(ws + off);                       off += (size_t)N * 4;
  int* partial = (int*)(ws + off);

  int zB = (N + 2047) / 2048;
  long n8 = (long)N * 16;
  int cvB = (int)((n8 + 2047) / 2048);
  prep_zero<<<128 + zB + cvB, 256, 0, stream>>>(Wm, w0, w1, w2, Wn, nodes,
                                                CmbT, W0T, W1T, W2nT, nodesBF,
                                                cnt, N, zB, n8);

  int eBlocks = (E + 255) / 256;
  hist_recv<<<eBlocks, 256, 0, stream>>>(receivers, cnt, E);

  const int CH = (N + 255) / 256;
  scanA<<<256, 256, 0, stream>>>(cnt, partial, N, CH);
  scanB<<<1, 256, 0, stream>>>(partial, offs, N);
  scanC<<<256, 256, 0, stream>>>(cnt, partial, offs, cursor, N, CH);

  scatter_ids<<<eBlocks, 256, 0, stream>>>(receivers, senders, cursor, pairs, E);

  int nodeBlocks = (N + 31) / 32;
  fused_node<<<nodeBlocks, 256, 0, stream>>>(nodesBF, edges, offs, pairs,
                                             CmbT, W0T, W1T, W2nT,
                                             b0, b1, b2, gam, bet, (float*)d_out, N);
}

// Round 13
// 243.528 us; speedup vs baseline: 1.5337x; 1.5337x over previous
//
#include <hip/hip_runtime.h>
#include <hip/hip_bf16.h>

typedef __attribute__((ext_vector_type(8))) short bf16x8;
typedef __attribute__((ext_vector_type(4))) float f32x4;

__device__ inline unsigned short f2bf(float x) {
  unsigned int u = __float_as_uint(x);
  unsigned int r = (u + 0x7fffu + ((u >> 16) & 1u)) >> 16;
  return (unsigned short)r;
}
__device__ inline float bf2f(unsigned short u) {
  return __uint_as_float(((unsigned int)u) << 16);
}

// ---- prep: weights (b<128) | zero cnt (128<=b<128+zB) | nodes->bf16 (rest) ----
__global__ __launch_bounds__(256) void prep_zero(
    const float* __restrict__ Wm, const float* __restrict__ w0,
    const float* __restrict__ w1, const float* __restrict__ w2,
    const float* __restrict__ Wn, const float* __restrict__ nodesF,
    unsigned short* __restrict__ CmbT, unsigned short* __restrict__ W0T,
    unsigned short* __restrict__ W1T, unsigned short* __restrict__ W2nT,
    unsigned short* __restrict__ nodesBF,
    int* __restrict__ cnt, int N, int zB, long n8)
{
  int b = blockIdx.x;
  if (b < 128) {
    int n = b;
    int k = threadIdx.x;
    CmbT[n*256 + k] = f2bf(Wm[k*128 + n]);
    W0T [n*256 + k] = f2bf(w0[k*128 + n]);
    W2nT[n*256 + k] = f2bf((k < 128) ? w2[k*128 + n] : Wn[(k-128)*128 + n]);
    if (k < 128) W1T[n*128 + k] = f2bf(w1[k*128 + n]);
  } else if (b < 128 + zB) {
    int base = (b - 128) * 2048 + threadIdx.x;
    #pragma unroll
    for (int it = 0; it < 8; ++it) {
      int i = base + it * 256;
      if (i < N) cnt[i] = 0;
    }
  } else {
    long base = (long)(b - 128 - zB) * 2048 + threadIdx.x;
    #pragma unroll
    for (int it = 0; it < 8; ++it) {
      long i = base + it * 256;
      if (i < n8) {
        const f32x4* p = reinterpret_cast<const f32x4*>(nodesF + i * 8);
        f32x4 a = p[0], c = p[1];
        bf16x8 o;
        o[0]=(short)f2bf(a[0]); o[1]=(short)f2bf(a[1]); o[2]=(short)f2bf(a[2]); o[3]=(short)f2bf(a[3]);
        o[4]=(short)f2bf(c[0]); o[5]=(short)f2bf(c[1]); o[6]=(short)f2bf(c[2]); o[7]=(short)f2bf(c[3]);
        *reinterpret_cast<bf16x8*>(nodesBF + i * 8) = o;
      }
    }
  }
}

// ---------------- counting sort of edges by receiver ----------------
__global__ __launch_bounds__(256) void hist_recv(
    const int* __restrict__ recv, int* __restrict__ cnt, int E)
{
  int e = blockIdx.x * 256 + threadIdx.x;
  if (e < E) atomicAdd(&cnt[recv[e]], 1);
}

// --- multi-block scan: A) chunk sums, B) scan 256 partials, C) apply ---
__global__ __launch_bounds__(256) void scanA(
    const int* __restrict__ cnt, int* __restrict__ partial, int N, int CH)
{
  __shared__ int sm[256];
  int b = blockIdx.x, t = threadIdx.x;
  int i = b * CH + t;
  int c = (t < CH && i < N) ? cnt[i] : 0;
  sm[t] = c; __syncthreads();
  for (int off = 128; off > 0; off >>= 1) {
    if (t < off) sm[t] += sm[t + off];
    __syncthreads();
  }
  if (t == 0) partial[b] = sm[0];
}

__global__ __launch_bounds__(256) void scanB(
    int* __restrict__ partial, int* __restrict__ offs, int N)
{
  __shared__ int sm[256];
  int t = threadIdx.x;
  int v = partial[t];
  sm[t] = v; __syncthreads();
  for (int off = 1; off < 256; off <<= 1) {
    int x = (t >= off) ? sm[t - off] : 0; __syncthreads();
    sm[t] += x; __syncthreads();
  }
  partial[t] = sm[t] - v;            // exclusive prefix
  if (t == 255) offs[N] = sm[255];   // total = E
}

__global__ __launch_bounds__(256) void scanC(
    const int* __restrict__ cnt, const int* __restrict__ partial,
    int* __restrict__ offs, int* __restrict__ cursor, int N, int CH)
{
  __shared__ int sm[256];
  int b = blockIdx.x, t = threadIdx.x;
  int i = b * CH + t;
  int c = (t < CH && i < N) ? cnt[i] : 0;
  sm[t] = c; __syncthreads();
  for (int off = 1; off < 256; off <<= 1) {
    int x = (t >= off) ? sm[t - off] : 0; __syncthreads();
    sm[t] += x; __syncthreads();
  }
  if (t < CH && i < N) {
    int excl = sm[t] - c + partial[b];
    offs[i] = excl;
    cursor[i] = excl;
  }
}

__global__ __launch_bounds__(256) void scatter_ids(
    const int* __restrict__ recv, const int* __restrict__ send,
    int* __restrict__ cursor, int2* __restrict__ pairs, int E)
{
  int e = blockIdx.x * 256 + threadIdx.x;
  if (e >= E) return;
  int pos = atomicAdd(&cursor[recv[e]], 1);
  pairs[pos] = make_int2(e, send[e]);
}

// ---------------- fused: gather-aggregate + 4 MFMA GEMMs + LayerNorm ---------
// 32-row tile, 4 waves; wave w: gathers 8 buckets, owns 32 GEMM cols.
__device__ inline bf16x8 ldsFragA(const unsigned short* tile, int rowBytes,
                                  int row, int kk, int lg) {
  int byteOff = row * rowBytes + ((((kk << 6) + (lg << 4))) ^ ((row & 7) << 4));
  return *reinterpret_cast<const bf16x8*>(
      reinterpret_cast<const char*>(tile) + byteOff);
}
__device__ inline bf16x8 glbFragB(const unsigned short* WT, int kElems,
                                  int n, int lr, int kk, int lg) {
  size_t el = (size_t)(n*16 + lr) * kElems + kk*32 + lg*8;
  return *reinterpret_cast<const bf16x8*>(WT + el);
}
__device__ inline bf16x8 fragA_nodesBF(const unsigned short* __restrict__ nodesBF,
                                       int grow, int kk, int lg) {
  return *reinterpret_cast<const bf16x8*>(nodesBF + (size_t)grow*128 + (kk << 5) + (lg << 3));
}

__global__ __launch_bounds__(256, 6) void fused_node(
    const unsigned short* __restrict__ nodesBF, const float* __restrict__ edgesF,
    const int* __restrict__ offs, const int2* __restrict__ pairs,
    const unsigned short* __restrict__ CmbT, const unsigned short* __restrict__ W0T,
    const unsigned short* __restrict__ W1T, const unsigned short* __restrict__ W2nT,
    const float* __restrict__ b0, const float* __restrict__ b1,
    const float* __restrict__ b2, const float* __restrict__ gam,
    const float* __restrict__ bet, float* __restrict__ out, int N)
{
  __shared__ unsigned short sS[32*256];   // 16KB gathered S tile; bufA/bufB alias
  __shared__ int sOffs[4][9];
  __shared__ float pS[4][32];
  __shared__ float pQ[4][32];

  unsigned short* bufA = sS;              // agg after G1; h1 after G3  [32][128]
  unsigned short* bufB = sS + 32*128;     // h0 after G2               [32][128]

  const int tid  = threadIdx.x;
  const int lane = tid & 63;
  const int w    = tid >> 6;           // wave 0..3
  const int lr = lane & 15;
  const int lg = lane >> 4;
  const int m0 = blockIdx.x * 32;

  // ---- gather: wave w aggregates nodes [m0+w*8, m0+w*8+8) ----
  {
    const int base = m0 + (w << 3);
    if (lane < 9) {
      int nidx = base + lane; if (nidx > N) nidx = N;
      sOffs[w][lane] = offs[nidx];
    }
    const int c4 = (lane & 31) * 4;
    const bool isNode = lane < 32;
    char* sSb = reinterpret_cast<char*>(sS);

    const int jstart = sOffs[w][0];
    const int jend   = sOffs[w][8];

    float4 acc = {0.f, 0.f, 0.f, 0.f};
    int nd = 0;
    int bound = sOffs[w][1];

    auto flush = [&]() {
      int row = (w << 3) + nd;
      ushort4 o;
      o.x = f2bf(acc.x); o.y = f2bf(acc.y); o.z = f2bf(acc.z); o.w = f2bf(acc.w);
      *reinterpret_cast<ushort4*>(sSb + row*512 + ((lane*8) ^ ((row & 7) << 4))) = o;
      acc.x = 0.f; acc.y = 0.f; acc.z = 0.f; acc.w = 0.f;
    };

    int j = jstart;
    if (j < jend) {
      const int jmax = jend - 1;
      int2 pb[8];
      #pragma unroll
      for (int k = 0; k < 8; ++k) pb[k] = pairs[min(j + k, jmax)];
      while (j < jend) {
        float4 v[8];
        if (isNode) {
          #pragma unroll
          for (int k = 0; k < 8; ++k) {
            ushort4 u = *reinterpret_cast<const ushort4*>(nodesBF + (size_t)pb[k].y*128 + c4);
            v[k].x = bf2f(u.x); v[k].y = bf2f(u.y); v[k].z = bf2f(u.z); v[k].w = bf2f(u.w);
          }
        } else {
          #pragma unroll
          for (int k = 0; k < 8; ++k)
            v[k] = *reinterpret_cast<const float4*>(edgesF + (size_t)pb[k].x*128 + c4);
        }
        int jn = j + 8;
        int2 pb2[8];
        if (jn < jend) {
          #pragma unroll
          for (int k = 0; k < 8; ++k) pb2[k] = pairs[min(jn + k, jmax)];
        }
        #pragma unroll
        for (int k = 0; k < 8; ++k) {
          int jj = j + k;
          if (jj < jend) {
            while (jj >= bound) {
              flush(); ++nd;
              bound = sOffs[w][nd + 1];
            }
            acc.x += v[k].x; acc.y += v[k].y; acc.z += v[k].z; acc.w += v[k].w;
          }
        }
        #pragma unroll
        for (int k = 0; k < 8; ++k) pb[k] = pb2[k];
        j = jn;
      }
    }
    while (nd < 8) { flush(); ++nd; }
  }

  f32x4 acc[2][2];   // row=rb*16+lg*4+i, col=w*32+nn*16+lr
  bf16x8 b[2][4];
  int garow[2];
  #pragma unroll
  for (int rb = 0; rb < 2; ++rb) {
    int g = m0 + rb*16 + lr; if (g > N-1) g = N-1;
    garow[rb] = g;
  }

  // G1 first-half B loads (global) issue before the barrier
  #pragma unroll
  for (int nn = 0; nn < 2; ++nn)
    #pragma unroll
    for (int kk = 0; kk < 4; ++kk)
      b[nn][kk] = glbFragB(CmbT, 256, w*2 + nn, lr, kk, lg);

  __syncthreads();   // S1: sS(gathered) staged

  // ======== GEMM1: agg = S(32x256) @ Wm ========
  #pragma unroll
  for (int rb = 0; rb < 2; ++rb)
    #pragma unroll
    for (int nn = 0; nn < 2; ++nn) { acc[rb][nn][0]=0.f; acc[rb][nn][1]=0.f; acc[rb][nn][2]=0.f; acc[rb][nn][3]=0.f; }
  #pragma unroll
  for (int rb = 0; rb < 2; ++rb)
    #pragma unroll
    for (int kk = 0; kk < 4; ++kk) {
      bf16x8 a = ldsFragA(sS, 512, rb*16 + lr, kk, lg);
      #pragma unroll
      for (int nn = 0; nn < 2; ++nn)
        acc[rb][nn] = __builtin_amdgcn_mfma_f32_16x16x32_bf16(a, b[nn][kk], acc[rb][nn], 0, 0, 0);
    }
  #pragma unroll
  for (int nn = 0; nn < 2; ++nn)
    #pragma unroll
    for (int kk = 0; kk < 4; ++kk)
      b[nn][kk] = glbFragB(CmbT, 256, w*2 + nn, lr, kk + 4, lg);
  #pragma unroll
  for (int rb = 0; rb < 2; ++rb)
    #pragma unroll
    for (int kk = 0; kk < 4; ++kk) {
      bf16x8 a = ldsFragA(sS, 512, rb*16 + lr, kk + 4, lg);
      #pragma unroll
      for (int nn = 0; nn < 2; ++nn)
        acc[rb][nn] = __builtin_amdgcn_mfma_f32_16x16x32_bf16(a, b[nn][kk], acc[rb][nn], 0, 0, 0);
    }
  __syncthreads();   // S2: all sS reads done before bufA overwrite

  // epilogue G1 -> bufA (agg)
  #pragma unroll
  for (int rb = 0; rb < 2; ++rb)
    #pragma unroll
    for (int nn = 0; nn < 2; ++nn) {
      int col = w*32 + nn*16 + lr;
      #pragma unroll
      for (int i = 0; i < 4; ++i) {
        int r = rb*16 + lg*4 + i;
        *reinterpret_cast<unsigned short*>(
            reinterpret_cast<char*>(bufA) + r*256 + ((col << 1) ^ ((r & 7) << 4))) = f2bf(acc[rb][nn][i]);
      }
    }
  // G2 first-half B loads before the barrier
  #pragma unroll
  for (int nn = 0; nn < 2; ++nn)
    #pragma unroll
    for (int kk = 0; kk < 4; ++kk)
      b[nn][kk] = glbFragB(W0T, 256, w*2 + nn, lr, kk, lg);
  __syncthreads();   // S3: bufA(agg) ready

  // ======== GEMM2: h0 = relu([nodes, agg] @ w0 + b0) -> bufB ========
  #pragma unroll
  for (int rb = 0; rb < 2; ++rb)
    #pragma unroll
    for (int nn = 0; nn < 2; ++nn) { acc[rb][nn][0]=0.f; acc[rb][nn][1]=0.f; acc[rb][nn][2]=0.f; acc[rb][nn][3]=0.f; }
  #pragma unroll
  for (int rb = 0; rb < 2; ++rb)
    #pragma unroll
    for (int kk = 0; kk < 4; ++kk) {
      bf16x8 a = fragA_nodesBF(nodesBF, garow[rb], kk, lg);
      #pragma unroll
      for (int nn = 0; nn < 2; ++nn)
        acc[rb][nn] = __builtin_amdgcn_mfma_f32_16x16x32_bf16(a, b[nn][kk], acc[rb][nn], 0, 0, 0);
    }
  #pragma unroll
  for (int nn = 0; nn < 2; ++nn)
    #pragma unroll
    for (int kk = 0; kk < 4; ++kk)
      b[nn][kk] = glbFragB(W0T, 256, w*2 + nn, lr, kk + 4, lg);
  #pragma unroll
  for (int rb = 0; rb < 2; ++rb)
    #pragma unroll
    for (int kk = 0; kk < 4; ++kk) {
      bf16x8 a = ldsFragA(bufA, 256, rb*16 + lr, kk, lg);
      #pragma unroll
      for (int nn = 0; nn < 2; ++nn)
        acc[rb][nn] = __builtin_amdgcn_mfma_f32_16x16x32_bf16(a, b[nn][kk], acc[rb][nn], 0, 0, 0);
    }
  // epilogue G2 -> bufB (disjoint; no barrier)
  #pragma unroll
  for (int nn = 0; nn < 2; ++nn) {
    int col = w*32 + nn*16 + lr;
    float bb = b0[col];
    #pragma unroll
    for (int rb = 0; rb < 2; ++rb)
      #pragma unroll
      for (int i = 0; i < 4; ++i) {
        int r = rb*16 + lg*4 + i;
        float x = fmaxf(acc[rb][nn][i] + bb, 0.f);
        *reinterpret_cast<unsigned short*>(
            reinterpret_cast<char*>(bufB) + r*256 + ((col << 1) ^ ((r & 7) << 4))) = f2bf(x);
      }
  }
  // G3 B loads (K=128)
  #pragma unroll
  for (int nn = 0; nn < 2; ++nn)
    #pragma unroll
    for (int kk = 0; kk < 4; ++kk)
      b[nn][kk] = glbFragB(W1T, 128, w*2 + nn, lr, kk, lg);
  __syncthreads();   // S4: bufB(h0) ready; all bufA reads done

  // ======== GEMM3: h1 = relu(h0 @ w1 + b1) -> bufA ========
  #pragma unroll
  for (int rb = 0; rb < 2; ++rb)
    #pragma unroll
    for (int nn = 0; nn < 2; ++nn) { acc[rb][nn][0]=0.f; acc[rb][nn][1]=0.f; acc[rb][nn][2]=0.f; acc[rb][nn][3]=0.f; }
  #pragma unroll
  for (int rb = 0; rb < 2; ++rb)
    #pragma unroll
    for (int kk = 0; kk < 4; ++kk) {
      bf16x8 a = ldsFragA(bufB, 256, rb*16 + lr, kk, lg);
      #pragma unroll
      for (int nn = 0; nn < 2; ++nn)
        acc[rb][nn] = __builtin_amdgcn_mfma_f32_16x16x32_bf16(a, b[nn][kk], acc[rb][nn], 0, 0, 0);
    }
  // epilogue G3 -> bufA
  #pragma unroll
  for (int nn = 0; nn < 2; ++nn) {
    int col = w*32 + nn*16 + lr;
    float bb = b1[col];
    #pragma unroll
    for (int rb = 0; rb < 2; ++rb)
      #pragma unroll
      for (int i = 0; i < 4; ++i) {
        int r = rb*16 + lg*4 + i;
        float x = fmaxf(acc[rb][nn][i] + bb, 0.f);
        *reinterpret_cast<unsigned short*>(
            reinterpret_cast<char*>(bufA) + r*256 + ((col << 1) ^ ((r & 7) << 4))) = f2bf(x);
      }
  }
  // G4 first-half B loads
  #pragma unroll
  for (int nn = 0; nn < 2; ++nn)
    #pragma unroll
    for (int kk = 0; kk < 4; ++kk)
      b[nn][kk] = glbFragB(W2nT, 256, w*2 + nn, lr, kk, lg);
  __syncthreads();   // S5: bufA(h1) ready; all bufB reads done

  // ======== GEMM4: o = [h1, nodes] @ [w2; Wnode] + b2, LayerNorm ========
  #pragma unroll
  for (int rb = 0; rb < 2; ++rb)
    #pragma unroll
    for (int nn = 0; nn < 2; ++nn) { acc[rb][nn][0]=0.f; acc[rb][nn][1]=0.f; acc[rb][nn][2]=0.f; acc[rb][nn][3]=0.f; }
  #pragma unroll
  for (int rb = 0; rb < 2; ++rb)
    #pragma unroll
    for (int kk = 0; kk < 4; ++kk) {
      bf16x8 a = ldsFragA(bufA, 256, rb*16 + lr, kk, lg);
      #pragma unroll
      for (int nn = 0; nn < 2; ++nn)
        acc[rb][nn] = __builtin_amdgcn_mfma_f32_16x16x32_bf16(a, b[nn][kk], acc[rb][nn], 0, 0, 0);
    }
  #pragma unroll
  for (int nn = 0; nn < 2; ++nn)
    #pragma unroll
    for (int kk = 0; kk < 4; ++kk)
      b[nn][kk] = glbFragB(W2nT, 256, w*2 + nn, lr, kk + 4, lg);
  #pragma unroll
  for (int rb = 0; rb < 2; ++rb)
    #pragma unroll
    for (int kk = 0; kk < 4; ++kk) {
      bf16x8 a = fragA_nodesBF(nodesBF, garow[rb], kk, lg);
      #pragma unroll
      for (int nn = 0; nn < 2; ++nn)
        acc[rb][nn] = __builtin_amdgcn_mfma_f32_16x16x32_bf16(a, b[nn][kk], acc[rb][nn], 0, 0, 0);
    }
  // bias
  #pragma unroll
  for (int nn = 0; nn < 2; ++nn) {
    float bb = b2[w*32 + nn*16 + lr];
    #pragma unroll
    for (int rb = 0; rb < 2; ++rb)
      #pragma unroll
      for (int i = 0; i < 4; ++i) acc[rb][nn][i] += bb;
  }

  // ---- LayerNorm: cross-wave row reduction via LDS partials ----
  float rs[2][4], rq[2][4];
  #pragma unroll
  for (int rb = 0; rb < 2; ++rb)
    #pragma unroll
    for (int i = 0; i < 4; ++i) {
      float a0 = acc[rb][0][i], a1 = acc[rb][1][i];
      rs[rb][i] = a0 + a1;
      rq[rb][i] = a0*a0 + a1*a1;
    }
  #pragma unroll
  for (int msk = 1; msk < 16; msk <<= 1)
    #pragma unroll
    for (int rb = 0; rb < 2; ++rb)
      #pragma unroll
      for (int i = 0; i < 4; ++i) {
        rs[rb][i] += __shfl_xor(rs[rb][i], msk);
        rq[rb][i] += __shfl_xor(rq[rb][i], msk);
      }
  if (lr == 0) {
    #pragma unroll
    for (int rb = 0; rb < 2; ++rb)
      #pragma unroll
      for (int i = 0; i < 4; ++i) {
        int r = rb*16 + lg*4 + i;
        pS[w][r] = rs[rb][i];
        pQ[w][r] = rq[rb][i];
      }
  }
  __syncthreads();

  float gmul[2], gadd[2];
  #pragma unroll
  for (int nn = 0; nn < 2; ++nn) {
    int col = w*32 + nn*16 + lr;
    gmul[nn] = gam[col]; gadd[nn] = bet[col];
  }
  #pragma unroll
  for (int rb = 0; rb < 2; ++rb)
    #pragma unroll
    for (int i = 0; i < 4; ++i) {
      int r = rb*16 + lg*4 + i;
      float sum = pS[0][r] + pS[1][r] + pS[2][r] + pS[3][r];
      float sq  = pQ[0][r] + pQ[1][r] + pQ[2][r] + pQ[3][r];
      float mean = sum * (1.f/128.f);
      float var  = fmaxf(sq * (1.f/128.f) - mean*mean, 0.f);
      float rstd = rsqrtf(var + 1e-6f);
      int grow = m0 + r;
      if (grow < N) {
        #pragma unroll
        for (int nn = 0; nn < 2; ++nn) {
          int col = w*32 + nn*16 + lr;
          out[(size_t)grow*128 + col] = (acc[rb][nn][i] - mean) * rstd * gmul[nn] + gadd[nn];
        }
      }
    }
}

extern "C" void kernel_launch(void* const* d_in, const int* in_sizes, int n_in,
                              void* d_out, int out_size, void* d_ws, size_t ws_size,
                              hipStream_t stream) {
  const float* nodes     = (const float*)d_in[0];
  const float* edges     = (const float*)d_in[1];
  const int*   senders   = (const int*)d_in[2];
  const int*   receivers = (const int*)d_in[3];
  const float* Wm  = (const float*)d_in[4];
  const float* Wn  = (const float*)d_in[5];
  const float* w0  = (const float*)d_in[6];
  const float* b0  = (const float*)d_in[7];
  const float* w1  = (const float*)d_in[8];
  const float* b1  = (const float*)d_in[9];
  const float* w2  = (const float*)d_in[10];
  const float* b2  = (const float*)d_in[11];
  const float* gam = (const float*)d_in[12];
  const float* bet = (const float*)d_in[13];
  const int N = in_sizes[0] / 128;
  const int E = in_sizes[1] / 128;

  char* ws = (char*)d_ws;
  size_t off = 0;
  unsigned short* nodesBF = (unsigned short*)(ws + off); off += (size_t)N * 128 * 2;
  int2* pairs = (int2*)(ws + off);                       off += (size_t)E * 8;
  unsigned short* CmbT = (unsigned short*)(ws + off);    off += 128*256*2;
  unsigned short* W0T  = (unsigned short*)(ws + off);    off += 128*256*2;
  unsigned short* W1T  = (unsigned short*)(ws + off);    off += 128*128*2;
  unsigned short* W2nT = (unsigned short*)(ws + off);    off += 128*256*2;
  int* cnt     = (int*)(ws + off);                       off += (size_t)N * 4;
  int* offs    = (int*)(ws + off);                       off += (size_t)(N + 1) * 4;
  int* cursor  = (int*)(ws + off);                       off += (size_t)N * 4;
  int* partial = (int*)(ws + off);

  int zB = (N + 2047) / 2048;
  long n8 = (long)N * 16;
  int cvB = (int)((n8 + 2047) / 2048);
  prep_zero<<<128 + zB + cvB, 256, 0, stream>>>(Wm, w0, w1, w2, Wn, nodes,
                                                CmbT, W0T, W1T, W2nT, nodesBF,
                                                cnt, N, zB, n8);

  int eBlocks = (E + 255) / 256;
  hist_recv<<<eBlocks, 256, 0, stream>>>(receivers, cnt, E);

  const int CH = (N + 255) / 256;
  scanA<<<256, 256, 0, stream>>>(cnt, partial, N, CH);
  scanB<<<1, 256, 0, stream>>>(partial, offs, N);
  scanC<<<256, 256, 0, stream>>>(cnt, partial, offs, cursor, N, CH);

  scatter_ids<<<eBlocks, 256, 0, stream>>>(receivers, senders, cursor, pairs, E);

  int nodeBlocks = (N + 31) / 32;
  fused_node<<<nodeBlocks, 256, 0, stream>>>(nodesBF, edges, offs, pairs,
                                             CmbT, W0T, W1T, W2nT,
                                             b0, b1, b2, gam, bet, (float*)d_out, N);
}

// Round 14
// 236.643 us; speedup vs baseline: 1.5784x; 1.0291x over previous
//
#include <hip/hip_runtime.h>
#include <hip/hip_bf16.h>

typedef __attribute__((ext_vector_type(8))) short bf16x8;
typedef __attribute__((ext_vector_type(4))) float f32x4;

__device__ inline unsigned short f2bf(float x) {
  unsigned int u = __float_as_uint(x);
  unsigned int r = (u + 0x7fffu + ((u >> 16) & 1u)) >> 16;
  return (unsigned short)r;
}
__device__ inline float bf2f(unsigned short u) {
  return __uint_as_float(((unsigned int)u) << 16);
}

// ---- prep: weights (b<128) | zero cnt (128<=b<128+zB) | nodes->bf16 (rest) ----
__global__ __launch_bounds__(256) void prep_zero(
    const float* __restrict__ Wm, const float* __restrict__ w0,
    const float* __restrict__ w1, const float* __restrict__ w2,
    const float* __restrict__ Wn, const float* __restrict__ nodesF,
    unsigned short* __restrict__ CmbT, unsigned short* __restrict__ W0T,
    unsigned short* __restrict__ W1T, unsigned short* __restrict__ W2nT,
    unsigned short* __restrict__ nodesBF,
    int* __restrict__ cnt, int N, int zB, long n8)
{
  int b = blockIdx.x;
  if (b < 128) {
    int n = b;
    int k = threadIdx.x;
    CmbT[n*256 + k] = f2bf(Wm[k*128 + n]);
    W0T [n*256 + k] = f2bf(w0[k*128 + n]);
    W2nT[n*256 + k] = f2bf((k < 128) ? w2[k*128 + n] : Wn[(k-128)*128 + n]);
    if (k < 128) W1T[n*128 + k] = f2bf(w1[k*128 + n]);
  } else if (b < 128 + zB) {
    int base = (b - 128) * 2048 + threadIdx.x;
    #pragma unroll
    for (int it = 0; it < 8; ++it) {
      int i = base + it * 256;
      if (i < N) cnt[i] = 0;
    }
  } else {
    long base = (long)(b - 128 - zB) * 2048 + threadIdx.x;
    #pragma unroll
    for (int it = 0; it < 8; ++it) {
      long i = base + it * 256;
      if (i < n8) {
        const f32x4* p = reinterpret_cast<const f32x4*>(nodesF + i * 8);
        f32x4 a = p[0], c = p[1];
        bf16x8 o;
        o[0]=(short)f2bf(a[0]); o[1]=(short)f2bf(a[1]); o[2]=(short)f2bf(a[2]); o[3]=(short)f2bf(a[3]);
        o[4]=(short)f2bf(c[0]); o[5]=(short)f2bf(c[1]); o[6]=(short)f2bf(c[2]); o[7]=(short)f2bf(c[3]);
        *reinterpret_cast<bf16x8*>(nodesBF + i * 8) = o;
      }
    }
  }
}

// ---------------- counting sort of edges by receiver ----------------
__global__ __launch_bounds__(256) void hist_recv(
    const int* __restrict__ recv, int* __restrict__ cnt, int E)
{
  int e = blockIdx.x * 256 + threadIdx.x;
  if (e < E) atomicAdd(&cnt[recv[e]], 1);
}

// --- scanA: per-chunk sums ---
__global__ __launch_bounds__(256) void scanA(
    const int* __restrict__ cnt, int* __restrict__ partial, int N, int CH)
{
  __shared__ int sm[256];
  int b = blockIdx.x, t = threadIdx.x;
  int i = b * CH + t;
  int c = (t < CH && i < N) ? cnt[i] : 0;
  sm[t] = c; __syncthreads();
  for (int off = 128; off > 0; off >>= 1) {
    if (t < off) sm[t] += sm[t + off];
    __syncthreads();
  }
  if (t == 0) partial[b] = sm[0];
}

// --- scanBC: each block re-scans the 256 partials locally, then applies ---
__global__ __launch_bounds__(256) void scanBC(
    const int* __restrict__ cnt, const int* __restrict__ partial,
    int* __restrict__ offs, int* __restrict__ cursor, int N, int CH)
{
  __shared__ int sp[256];
  __shared__ int sv[256];
  __shared__ int sm[256];
  int b = blockIdx.x, t = threadIdx.x;
  int v = partial[t];
  sp[t] = v; sv[t] = v; __syncthreads();
  for (int off = 1; off < 256; off <<= 1) {
    int x = (t >= off) ? sp[t - off] : 0; __syncthreads();
    sp[t] += x; __syncthreads();
  }
  // exclusive prefix for this block's chunk
  const int base = sp[b] - sv[b];
  if (b == 0 && t == 255) offs[N] = sp[255];
  // chunk exclusive scan
  int i = b * CH + t;
  int c = (t < CH && i < N) ? cnt[i] : 0;
  sm[t] = c; __syncthreads();
  for (int off = 1; off < 256; off <<= 1) {
    int x = (t >= off) ? sm[t - off] : 0; __syncthreads();
    sm[t] += x; __syncthreads();
  }
  if (t < CH && i < N) {
    int excl = sm[t] - c + base;
    offs[i] = excl;
    cursor[i] = excl;
  }
}

__global__ __launch_bounds__(256) void scatter_ids(
    const int* __restrict__ recv, const int* __restrict__ send,
    int* __restrict__ cursor, int2* __restrict__ pairs, int E)
{
  int e = blockIdx.x * 256 + threadIdx.x;
  if (e >= E) return;
  int pos = atomicAdd(&cursor[recv[e]], 1);
  pairs[pos] = make_int2(e, send[e]);
}

// ---------------- fused: gather-aggregate + 4 MFMA GEMMs + LayerNorm ---------
// 32-row tile, 4 waves; wave w: gathers 8 buckets, owns 32 GEMM cols.
__device__ inline bf16x8 ldsFragA(const unsigned short* tile, int rowBytes,
                                  int row, int kk, int lg) {
  int byteOff = row * rowBytes + ((((kk << 6) + (lg << 4))) ^ ((row & 7) << 4));
  return *reinterpret_cast<const bf16x8*>(
      reinterpret_cast<const char*>(tile) + byteOff);
}
__device__ inline bf16x8 glbFragB(const unsigned short* WT, int kElems,
                                  int n, int lr, int kk, int lg) {
  size_t el = (size_t)(n*16 + lr) * kElems + kk*32 + lg*8;
  return *reinterpret_cast<const bf16x8*>(WT + el);
}
__device__ inline bf16x8 fragA_nodesBF(const unsigned short* __restrict__ nodesBF,
                                       int grow, int kk, int lg) {
  return *reinterpret_cast<const bf16x8*>(nodesBF + (size_t)grow*128 + (kk << 5) + (lg << 3));
}

__global__ __launch_bounds__(256, 5) void fused_node(
    const unsigned short* __restrict__ nodesBF, const float* __restrict__ edgesF,
    const int* __restrict__ offs, const int2* __restrict__ pairs,
    const unsigned short* __restrict__ CmbT, const unsigned short* __restrict__ W0T,
    const unsigned short* __restrict__ W1T, const unsigned short* __restrict__ W2nT,
    const float* __restrict__ b0, const float* __restrict__ b1,
    const float* __restrict__ b2, const float* __restrict__ gam,
    const float* __restrict__ bet, float* __restrict__ out, int N)
{
  __shared__ unsigned short sS[32*256];   // 16KB gathered S tile; bufA/bufB alias
  __shared__ int sOffs[4][9];
  __shared__ float pS[4][32];
  __shared__ float pQ[4][32];

  unsigned short* bufA = sS;              // agg after G1; h1 after G3  [32][128]
  unsigned short* bufB = sS + 32*128;     // h0 after G2               [32][128]

  const int tid  = threadIdx.x;
  const int lane = tid & 63;
  const int w    = tid >> 6;           // wave 0..3
  const int lr = lane & 15;
  const int lg = lane >> 4;
  const int m0 = blockIdx.x * 32;

  // ---- gather: wave w aggregates nodes [m0+w*8, m0+w*8+8) ----
  {
    const int base = m0 + (w << 3);
    if (lane < 9) {
      int nidx = base + lane; if (nidx > N) nidx = N;
      sOffs[w][lane] = offs[nidx];
    }
    const int c4 = (lane & 31) * 4;
    const bool isNode = lane < 32;
    char* sSb = reinterpret_cast<char*>(sS);

    const int jstart = sOffs[w][0];
    const int jend   = sOffs[w][8];

    float4 acc = {0.f, 0.f, 0.f, 0.f};
    int nd = 0;
    int bound = sOffs[w][1];

    auto flush = [&]() {
      int row = (w << 3) + nd;
      ushort4 o;
      o.x = f2bf(acc.x); o.y = f2bf(acc.y); o.z = f2bf(acc.z); o.w = f2bf(acc.w);
      *reinterpret_cast<ushort4*>(sSb + row*512 + ((lane*8) ^ ((row & 7) << 4))) = o;
      acc.x = 0.f; acc.y = 0.f; acc.z = 0.f; acc.w = 0.f;
    };

    int j = jstart;
    if (j < jend) {
      const int jmax = jend - 1;
      int2 pb[8];
      #pragma unroll
      for (int k = 0; k < 8; ++k) pb[k] = pairs[min(j + k, jmax)];
      while (j < jend) {
        float4 v[8];
        if (isNode) {
          #pragma unroll
          for (int k = 0; k < 8; ++k) {
            ushort4 u = *reinterpret_cast<const ushort4*>(nodesBF + (size_t)pb[k].y*128 + c4);
            v[k].x = bf2f(u.x); v[k].y = bf2f(u.y); v[k].z = bf2f(u.z); v[k].w = bf2f(u.w);
          }
        } else {
          #pragma unroll
          for (int k = 0; k < 8; ++k)
            v[k] = *reinterpret_cast<const float4*>(edgesF + (size_t)pb[k].x*128 + c4);
        }
        int jn = j + 8;
        int2 pb2[8];
        if (jn < jend) {
          #pragma unroll
          for (int k = 0; k < 8; ++k) pb2[k] = pairs[min(jn + k, jmax)];
        }
        #pragma unroll
        for (int k = 0; k < 8; ++k) {
          int jj = j + k;
          if (jj < jend) {
            while (jj >= bound) {
              flush(); ++nd;
              bound = sOffs[w][nd + 1];
            }
            acc.x += v[k].x; acc.y += v[k].y; acc.z += v[k].z; acc.w += v[k].w;
          }
        }
        #pragma unroll
        for (int k = 0; k < 8; ++k) pb[k] = pb2[k];
        j = jn;
      }
    }
    while (nd < 8) { flush(); ++nd; }
  }

  f32x4 acc[2][2];   // row=rb*16+lg*4+i, col=w*32+nn*16+lr
  bf16x8 b[2][4];
  int garow[2];
  #pragma unroll
  for (int rb = 0; rb < 2; ++rb) {
    int g = m0 + rb*16 + lr; if (g > N-1) g = N-1;
    garow[rb] = g;
  }

  // G1 first-half B loads (global) issue before the barrier
  #pragma unroll
  for (int nn = 0; nn < 2; ++nn)
    #pragma unroll
    for (int kk = 0; kk < 4; ++kk)
      b[nn][kk] = glbFragB(CmbT, 256, w*2 + nn, lr, kk, lg);

  __syncthreads();   // S1: sS(gathered) staged

  // ======== GEMM1: agg = S(32x256) @ Wm ========
  #pragma unroll
  for (int rb = 0; rb < 2; ++rb)
    #pragma unroll
    for (int nn = 0; nn < 2; ++nn) { acc[rb][nn][0]=0.f; acc[rb][nn][1]=0.f; acc[rb][nn][2]=0.f; acc[rb][nn][3]=0.f; }
  #pragma unroll
  for (int rb = 0; rb < 2; ++rb)
    #pragma unroll
    for (int kk = 0; kk < 4; ++kk) {
      bf16x8 a = ldsFragA(sS, 512, rb*16 + lr, kk, lg);
      #pragma unroll
      for (int nn = 0; nn < 2; ++nn)
        acc[rb][nn] = __builtin_amdgcn_mfma_f32_16x16x32_bf16(a, b[nn][kk], acc[rb][nn], 0, 0, 0);
    }
  #pragma unroll
  for (int nn = 0; nn < 2; ++nn)
    #pragma unroll
    for (int kk = 0; kk < 4; ++kk)
      b[nn][kk] = glbFragB(CmbT, 256, w*2 + nn, lr, kk + 4, lg);
  #pragma unroll
  for (int rb = 0; rb < 2; ++rb)
    #pragma unroll
    for (int kk = 0; kk < 4; ++kk) {
      bf16x8 a = ldsFragA(sS, 512, rb*16 + lr, kk + 4, lg);
      #pragma unroll
      for (int nn = 0; nn < 2; ++nn)
        acc[rb][nn] = __builtin_amdgcn_mfma_f32_16x16x32_bf16(a, b[nn][kk], acc[rb][nn], 0, 0, 0);
    }
  __syncthreads();   // S2: all sS reads done before bufA overwrite

  // epilogue G1 -> bufA (agg)
  #pragma unroll
  for (int rb = 0; rb < 2; ++rb)
    #pragma unroll
    for (int nn = 0; nn < 2; ++nn) {
      int col = w*32 + nn*16 + lr;
      #pragma unroll
      for (int i = 0; i < 4; ++i) {
        int r = rb*16 + lg*4 + i;
        *reinterpret_cast<unsigned short*>(
            reinterpret_cast<char*>(bufA) + r*256 + ((col << 1) ^ ((r & 7) << 4))) = f2bf(acc[rb][nn][i]);
      }
    }
  // G2 first-half B loads before the barrier
  #pragma unroll
  for (int nn = 0; nn < 2; ++nn)
    #pragma unroll
    for (int kk = 0; kk < 4; ++kk)
      b[nn][kk] = glbFragB(W0T, 256, w*2 + nn, lr, kk, lg);
  __syncthreads();   // S3: bufA(agg) ready

  // ======== GEMM2: h0 = relu([nodes, agg] @ w0 + b0) -> bufB ========
  #pragma unroll
  for (int rb = 0; rb < 2; ++rb)
    #pragma unroll
    for (int nn = 0; nn < 2; ++nn) { acc[rb][nn][0]=0.f; acc[rb][nn][1]=0.f; acc[rb][nn][2]=0.f; acc[rb][nn][3]=0.f; }
  #pragma unroll
  for (int rb = 0; rb < 2; ++rb)
    #pragma unroll
    for (int kk = 0; kk < 4; ++kk) {
      bf16x8 a = fragA_nodesBF(nodesBF, garow[rb], kk, lg);
      #pragma unroll
      for (int nn = 0; nn < 2; ++nn)
        acc[rb][nn] = __builtin_amdgcn_mfma_f32_16x16x32_bf16(a, b[nn][kk], acc[rb][nn], 0, 0, 0);
    }
  #pragma unroll
  for (int nn = 0; nn < 2; ++nn)
    #pragma unroll
    for (int kk = 0; kk < 4; ++kk)
      b[nn][kk] = glbFragB(W0T, 256, w*2 + nn, lr, kk + 4, lg);
  #pragma unroll
  for (int rb = 0; rb < 2; ++rb)
    #pragma unroll
    for (int kk = 0; kk < 4; ++kk) {
      bf16x8 a = ldsFragA(bufA, 256, rb*16 + lr, kk, lg);
      #pragma unroll
      for (int nn = 0; nn < 2; ++nn)
        acc[rb][nn] = __builtin_amdgcn_mfma_f32_16x16x32_bf16(a, b[nn][kk], acc[rb][nn], 0, 0, 0);
    }
  // epilogue G2 -> bufB (disjoint; no barrier)
  #pragma unroll
  for (int nn = 0; nn < 2; ++nn) {
    int col = w*32 + nn*16 + lr;
    float bb = b0[col];
    #pragma unroll
    for (int rb = 0; rb < 2; ++rb)
      #pragma unroll
      for (int i = 0; i < 4; ++i) {
        int r = rb*16 + lg*4 + i;
        float x = fmaxf(acc[rb][nn][i] + bb, 0.f);
        *reinterpret_cast<unsigned short*>(
            reinterpret_cast<char*>(bufB) + r*256 + ((col << 1) ^ ((r & 7) << 4))) = f2bf(x);
      }
  }
  // G3 B loads (K=128)
  #pragma unroll
  for (int nn = 0; nn < 2; ++nn)
    #pragma unroll
    for (int kk = 0; kk < 4; ++kk)
      b[nn][kk] = glbFragB(W1T, 128, w*2 + nn, lr, kk, lg);
  __syncthreads();   // S4: bufB(h0) ready; all bufA reads done

  // ======== GEMM3: h1 = relu(h0 @ w1 + b1) -> bufA ========
  #pragma unroll
  for (int rb = 0; rb < 2; ++rb)
    #pragma unroll
    for (int nn = 0; nn < 2; ++nn) { acc[rb][nn][0]=0.f; acc[rb][nn][1]=0.f; acc[rb][nn][2]=0.f; acc[rb][nn][3]=0.f; }
  #pragma unroll
  for (int rb = 0; rb < 2; ++rb)
    #pragma unroll
    for (int kk = 0; kk < 4; ++kk) {
      bf16x8 a = ldsFragA(bufB, 256, rb*16 + lr, kk, lg);
      #pragma unroll
      for (int nn = 0; nn < 2; ++nn)
        acc[rb][nn] = __builtin_amdgcn_mfma_f32_16x16x32_bf16(a, b[nn][kk], acc[rb][nn], 0, 0, 0);
    }
  // epilogue G3 -> bufA
  #pragma unroll
  for (int nn = 0; nn < 2; ++nn) {
    int col = w*32 + nn*16 + lr;
    float bb = b1[col];
    #pragma unroll
    for (int rb = 0; rb < 2; ++rb)
      #pragma unroll
      for (int i = 0; i < 4; ++i) {
        int r = rb*16 + lg*4 + i;
        float x = fmaxf(acc[rb][nn][i] + bb, 0.f);
        *reinterpret_cast<unsigned short*>(
            reinterpret_cast<char*>(bufA) + r*256 + ((col << 1) ^ ((r & 7) << 4))) = f2bf(x);
      }
  }
  // G4 first-half B loads
  #pragma unroll
  for (int nn = 0; nn < 2; ++nn)
    #pragma unroll
    for (int kk = 0; kk < 4; ++kk)
      b[nn][kk] = glbFragB(W2nT, 256, w*2 + nn, lr, kk, lg);
  __syncthreads();   // S5: bufA(h1) ready; all bufB reads done

  // ======== GEMM4: o = [h1, nodes] @ [w2; Wnode] + b2, LayerNorm ========
  #pragma unroll
  for (int rb = 0; rb < 2; ++rb)
    #pragma unroll
    for (int nn = 0; nn < 2; ++nn) { acc[rb][nn][0]=0.f; acc[rb][nn][1]=0.f; acc[rb][nn][2]=0.f; acc[rb][nn][3]=0.f; }
  #pragma unroll
  for (int rb = 0; rb < 2; ++rb)
    #pragma unroll
    for (int kk = 0; kk < 4; ++kk) {
      bf16x8 a = ldsFragA(bufA, 256, rb*16 + lr, kk, lg);
      #pragma unroll
      for (int nn = 0; nn < 2; ++nn)
        acc[rb][nn] = __builtin_amdgcn_mfma_f32_16x16x32_bf16(a, b[nn][kk], acc[rb][nn], 0, 0, 0);
    }
  #pragma unroll
  for (int nn = 0; nn < 2; ++nn)
    #pragma unroll
    for (int kk = 0; kk < 4; ++kk)
      b[nn][kk] = glbFragB(W2nT, 256, w*2 + nn, lr, kk + 4, lg);
  #pragma unroll
  for (int rb = 0; rb < 2; ++rb)
    #pragma unroll
    for (int kk = 0; kk < 4; ++kk) {
      bf16x8 a = fragA_nodesBF(nodesBF, garow[rb], kk, lg);
      #pragma unroll
      for (int nn = 0; nn < 2; ++nn)
        acc[rb][nn] = __builtin_amdgcn_mfma_f32_16x16x32_bf16(a, b[nn][kk], acc[rb][nn], 0, 0, 0);
    }
  // bias
  #pragma unroll
  for (int nn = 0; nn < 2; ++nn) {
    float bb = b2[w*32 + nn*16 + lr];
    #pragma unroll
    for (int rb = 0; rb < 2; ++rb)
      #pragma unroll
      for (int i = 0; i < 4; ++i) acc[rb][nn][i] += bb;
  }

  // ---- LayerNorm: cross-wave row reduction via LDS partials ----
  float rs[2][4], rq[2][4];
  #pragma unroll
  for (int rb = 0; rb < 2; ++rb)
    #pragma unroll
    for (int i = 0; i < 4; ++i) {
      float a0 = acc[rb][0][i], a1 = acc[rb][1][i];
      rs[rb][i] = a0 + a1;
      rq[rb][i] = a0*a0 + a1*a1;
    }
  #pragma unroll
  for (int msk = 1; msk < 16; msk <<= 1)
    #pragma unroll
    for (int rb = 0; rb < 2; ++rb)
      #pragma unroll
      for (int i = 0; i < 4; ++i) {
        rs[rb][i] += __shfl_xor(rs[rb][i], msk);
        rq[rb][i] += __shfl_xor(rq[rb][i], msk);
      }
  if (lr == 0) {
    #pragma unroll
    for (int rb = 0; rb < 2; ++rb)
      #pragma unroll
      for (int i = 0; i < 4; ++i) {
        int r = rb*16 + lg*4 + i;
        pS[w][r] = rs[rb][i];
        pQ[w][r] = rq[rb][i];
      }
  }
  __syncthreads();

  float gmul[2], gadd[2];
  #pragma unroll
  for (int nn = 0; nn < 2; ++nn) {
    int col = w*32 + nn*16 + lr;
    gmul[nn] = gam[col]; gadd[nn] = bet[col];
  }
  #pragma unroll
  for (int rb = 0; rb < 2; ++rb)
    #pragma unroll
    for (int i = 0; i < 4; ++i) {
      int r = rb*16 + lg*4 + i;
      float sum = pS[0][r] + pS[1][r] + pS[2][r] + pS[3][r];
      float sq  = pQ[0][r] + pQ[1][r] + pQ[2][r] + pQ[3][r];
      float mean = sum * (1.f/128.f);
      float var  = fmaxf(sq * (1.f/128.f) - mean*mean, 0.f);
      float rstd = rsqrtf(var + 1e-6f);
      int grow = m0 + r;
      if (grow < N) {
        #pragma unroll
        for (int nn = 0; nn < 2; ++nn) {
          int col = w*32 + nn*16 + lr;
          out[(size_t)grow*128 + col] = (acc[rb][nn][i] - mean) * rstd * gmul[nn] + gadd[nn];
        }
      }
    }
}

extern "C" void kernel_launch(void* const* d_in, const int* in_sizes, int n_in,
                              void* d_out, int out_size, void* d_ws, size_t ws_size,
                              hipStream_t stream) {
  const float* nodes     = (const float*)d_in[0];
  const float* edges     = (const float*)d_in[1];
  const int*   senders   = (const int*)d_in[2];
  const int*   receivers = (const int*)d_in[3];
  const float* Wm  = (const float*)d_in[4];
  const float* Wn  = (const float*)d_in[5];
  const float* w0  = (const float*)d_in[6];
  const float* b0  = (const float*)d_in[7];
  const float* w1  = (const float*)d_in[8];
  const float* b1  = (const float*)d_in[9];
  const float* w2  = (const float*)d_in[10];
  const float* b2  = (const float*)d_in[11];
  const float* gam = (const float*)d_in[12];
  const float* bet = (const float*)d_in[13];
  const int N = in_sizes[0] / 128;
  const int E = in_sizes[1] / 128;

  char* ws = (char*)d_ws;
  size_t off = 0;
  unsigned short* nodesBF = (unsigned short*)(ws + off); off += (size_t)N * 128 * 2;
  int2* pairs = (int2*)(ws + off);                       off += (size_t)E * 8;
  unsigned short* CmbT = (unsigned short*)(ws + off);    off += 128*256*2;
  unsigned short* W0T  = (unsigned short*)(ws + off);    off += 128*256*2;
  unsigned short* W1T  = (unsigned short*)(ws + off);    off += 128*128*2;
  unsigned short* W2nT = (unsigned short*)(ws + off);    off += 128*256*2;
  int* cnt     = (int*)(ws + off);                       off += (size_t)N * 4;
  int* offs    = (int*)(ws + off);                       off += (size_t)(N + 1) * 4;
  int* cursor  = (int*)(ws + off);                       off += (size_t)N * 4;
  int* partial = (int*)(ws + off);

  int zB = (N + 2047) / 2048;
  long n8 = (long)N * 16;
  int cvB = (int)((n8 + 2047) / 2048);
  prep_zero<<<128 + zB + cvB, 256, 0, stream>>>(Wm, w0, w1, w2, Wn, nodes,
                                                CmbT, W0T, W1T, W2nT, nodesBF,
                                                cnt, N, zB, n8);

  int eBlocks = (E + 255) / 256;
  hist_recv<<<eBlocks, 256, 0, stream>>>(receivers, cnt, E);

  const int CH = (N + 255) / 256;
  scanA<<<256, 256, 0, stream>>>(cnt, partial, N, CH);
  scanBC<<<256, 256, 0, stream>>>(cnt, partial, offs, cursor, N, CH);

  scatter_ids<<<eBlocks, 256, 0, stream>>>(receivers, senders, cursor, pairs, E);

  int nodeBlocks = (N + 31) / 32;
  fused_node<<<nodeBlocks, 256, 0, stream>>>(nodesBF, edges, offs, pairs,
                                             CmbT, W0T, W1T, W2nT,
                                             b0, b1, b2, gam, bet, (float*)d_out, N);
}